// Round 1
// baseline (1477.189 us; speedup 1.0000x reference)
//
#include <hip/hip_runtime.h>
#include <cfloat>
#include <cmath>

#define NROWS 32768
#define DDIM  512
#define KCODES 2048

// output layout (floats): [loss][q_st N*512][perplexity][encodings N*K]
#define OUT_Q    1
#define OUT_PERP 16777217
#define OUT_ENC  16777218

// scratch offsets in floats, relative to S = d_out + OUT_ENC + 2 (16B aligned)
#define H_OFF     0
#define HT_OFF    16777216
#define EMBT_OFF  33554432
#define WT_OFF    34603008
#define XT_OFF    34865152
#define ENORM_OFF 51642368

__global__ __launch_bounds__(256) void ktranspose(const float* __restrict__ src,
                                                  float* __restrict__ dst,
                                                  int R, int C) {
  __shared__ float tile[32][33];
  const int bc = blockIdx.x * 32;
  const int br = blockIdx.y * 32;
  const int tx = threadIdx.x & 31;
  const int ty = threadIdx.x >> 5;
#pragma unroll
  for (int i = 0; i < 32; i += 8)
    tile[ty + i][tx] = src[(size_t)(br + ty + i) * C + bc + tx];
  __syncthreads();
#pragma unroll
  for (int i = 0; i < 32; i += 8)
    dst[(size_t)(bc + ty + i) * R + br + tx] = tile[tx][ty + i];
}

__global__ __launch_bounds__(64) void kenorm(const float* __restrict__ emb,
                                             float* __restrict__ enorms) {
  const int k = blockIdx.x;
  const int t = threadIdx.x;
  float s = 0.f;
#pragma unroll
  for (int i = 0; i < 8; ++i) {
    const float v = emb[k * DDIM + t + i * 64];
    s = fmaf(v, v, s);
  }
#pragma unroll
  for (int off = 32; off > 0; off >>= 1) s += __shfl_down(s, off);
  if (t == 0) enorms[k] = s;
}

// h = X @ W^T + b, X = concat(x0,x1) (via pre-transposed xT, WT).
// Writes h [N][512] and hT [512][N].
__global__ __launch_bounds__(256) void kgemm1(const float* __restrict__ xT,
    const float* __restrict__ WT, const float* __restrict__ bias,
    float* __restrict__ h, float* __restrict__ hT) {
  __shared__ float Hs[64 * 64];
  __shared__ float Es[64 * 128];
  const int t  = threadIdx.x;
  const int r0 = blockIdx.x * 64;
  const int j0 = blockIdx.y * 128;
  const int tc = t & 15;
  const int tr = t >> 4;
  float acc[4][8];
#pragma unroll
  for (int a = 0; a < 4; ++a)
#pragma unroll
    for (int b2 = 0; b2 < 8; ++b2) acc[a][b2] = 0.f;

  for (int dc = 0; dc < 8; ++dc) {
#pragma unroll
    for (int j = 0; j < 4; ++j) {
      const int dd = j * 16 + (t >> 4);
      const int f  = t & 15;
      *(float4*)&Hs[dd * 64 + f * 4] =
          *(const float4*)&xT[(dc * 64 + dd) * NROWS + r0 + f * 4];
    }
#pragma unroll
    for (int j = 0; j < 8; ++j) {
      const int dd = j * 8 + (t >> 5);
      const int c  = t & 31;
      *(float4*)&Es[dd * 128 + c * 4] =
          *(const float4*)&WT[(dc * 64 + dd) * DDIM + j0 + c * 4];
    }
    __syncthreads();
#pragma unroll 16
    for (int di = 0; di < 64; ++di) {
      const float4 ha = *(const float4*)&Hs[di * 64 + tr * 4];
      const float4 e0 = *(const float4*)&Es[di * 128 + tc * 4];
      const float4 e1 = *(const float4*)&Es[di * 128 + 64 + tc * 4];
      const float hv[4] = {ha.x, ha.y, ha.z, ha.w};
      const float ev[8] = {e0.x, e0.y, e0.z, e0.w, e1.x, e1.y, e1.z, e1.w};
#pragma unroll
      for (int rr = 0; rr < 4; ++rr)
#pragma unroll
        for (int cc = 0; cc < 8; ++cc)
          acc[rr][cc] = fmaf(hv[rr], ev[cc], acc[rr][cc]);
    }
    __syncthreads();
  }
#pragma unroll
  for (int g = 0; g < 2; ++g) {
    const int j = j0 + g * 64 + tc * 4;
    const float4 bv = *(const float4*)&bias[j];
    const float bb[4] = {bv.x, bv.y, bv.z, bv.w};
#pragma unroll
    for (int rr = 0; rr < 4; ++rr) {
      const int r = r0 + tr * 4 + rr;
      float4 st;
      st.x = acc[rr][g * 4 + 0] + bb[0];
      st.y = acc[rr][g * 4 + 1] + bb[1];
      st.z = acc[rr][g * 4 + 2] + bb[2];
      st.w = acc[rr][g * 4 + 3] + bb[3];
      *(float4*)&h[r * DDIM + j] = st;
      hT[(j + 0) * NROWS + r] = st.x;
      hT[(j + 1) * NROWS + r] = st.y;
      hT[(j + 2) * NROWS + r] = st.z;
      hT[(j + 3) * NROWS + r] = st.w;
    }
  }
}

// per-row argmin_k ( ||e_k||^2 - 2 h.e_k )  over all K codes
__global__ __launch_bounds__(256) void kdist(const float* __restrict__ hT,
    const float* __restrict__ embT, const float* __restrict__ enorms,
    int* __restrict__ idx_out) {
  __shared__ float Hs[64 * 64];
  __shared__ float Es[64 * 128];
  const int t  = threadIdx.x;
  const int r0 = blockIdx.x * 64;
  const int tc = t & 15;
  const int tr = t >> 4;
  float bestv[4];
  int   bestk[4];
#pragma unroll
  for (int rr = 0; rr < 4; ++rr) { bestv[rr] = FLT_MAX; bestk[rr] = 0; }

  for (int kt = 0; kt < 16; ++kt) {
    float acc[4][8];
#pragma unroll
    for (int a = 0; a < 4; ++a)
#pragma unroll
      for (int b2 = 0; b2 < 8; ++b2) acc[a][b2] = 0.f;

    for (int dc = 0; dc < 8; ++dc) {
#pragma unroll
      for (int j = 0; j < 4; ++j) {
        const int dd = j * 16 + (t >> 4);
        const int f  = t & 15;
        *(float4*)&Hs[dd * 64 + f * 4] =
            *(const float4*)&hT[(dc * 64 + dd) * NROWS + r0 + f * 4];
      }
#pragma unroll
      for (int j = 0; j < 8; ++j) {
        const int dd = j * 8 + (t >> 5);
        const int c  = t & 31;
        *(float4*)&Es[dd * 128 + c * 4] =
            *(const float4*)&embT[(dc * 64 + dd) * KCODES + kt * 128 + c * 4];
      }
      __syncthreads();
#pragma unroll 16
      for (int di = 0; di < 64; ++di) {
        const float4 ha = *(const float4*)&Hs[di * 64 + tr * 4];
        const float4 e0 = *(const float4*)&Es[di * 128 + tc * 4];
        const float4 e1 = *(const float4*)&Es[di * 128 + 64 + tc * 4];
        const float hv[4] = {ha.x, ha.y, ha.z, ha.w};
        const float ev[8] = {e0.x, e0.y, e0.z, e0.w, e1.x, e1.y, e1.z, e1.w};
#pragma unroll
        for (int rr = 0; rr < 4; ++rr)
#pragma unroll
          for (int cc = 0; cc < 8; ++cc)
            acc[rr][cc] = fmaf(hv[rr], ev[cc], acc[rr][cc]);
      }
      __syncthreads();
    }
#pragma unroll
    for (int g = 0; g < 2; ++g) {
#pragma unroll
      for (int cc = 0; cc < 4; ++cc) {
        const int k = kt * 128 + g * 64 + tc * 4 + cc;
        const float en = enorms[k];
#pragma unroll
        for (int rr = 0; rr < 4; ++rr) {
          const float s = fmaf(-2.f, acc[rr][g * 4 + cc], en);
          if (s < bestv[rr]) { bestv[rr] = s; bestk[rr] = k; }
        }
      }
    }
  }
  __syncthreads();
  float* rv = Hs;          // reuse LDS
  int*   rk = (int*)Es;
#pragma unroll
  for (int rr = 0; rr < 4; ++rr) {
    rv[(tr * 4 + rr) * 16 + tc] = bestv[rr];
    rk[(tr * 4 + rr) * 16 + tc] = bestk[rr];
  }
  __syncthreads();
  if (t < 64) {
    float bv = rv[t * 16];
    int   bk = rk[t * 16];
#pragma unroll
    for (int c = 1; c < 16; ++c) {
      const float v = rv[t * 16 + c];
      const int  k2 = rk[t * 16 + c];
      if (v < bv || (v == bv && k2 < bk)) { bv = v; bk = k2; }
    }
    idx_out[r0 + t] = bk;
  }
}

// q_st = h + (e - h), write flat at d_out+1; accumulate loss sum
__global__ __launch_bounds__(256) void kquant(const float* __restrict__ h,
    const float* __restrict__ emb, const int* __restrict__ idx,
    float* __restrict__ qout, double* __restrict__ loss_accum) {
  const int tid = blockIdx.x * 256 + threadIdx.x;
  float ls = 0.f;
#pragma unroll
  for (int i = 0; i < 4; ++i) {
    const int f = tid + i * 4194304;
    const int n = f >> 9;
    const int c = f & 511;
    const float hv = h[f];
    const float ev = emb[idx[n] * DDIM + c];
    qout[f] = hv + (ev - hv);
    const float d = ev - hv;
    ls = fmaf(d, d, ls);
  }
  double s = (double)ls;
#pragma unroll
  for (int off = 32; off > 0; off >>= 1) s += __shfl_down(s, off);
  __shared__ double sred[4];
  if ((threadIdx.x & 63) == 0) sred[threadIdx.x >> 6] = s;
  __syncthreads();
  if (threadIdx.x == 0)
    atomicAdd(loss_accum, sred[0] + sred[1] + sred[2] + sred[3]);
}

__global__ __launch_bounds__(256) void khist(const int* __restrict__ idx,
                                             int* __restrict__ counts) {
  const int n = blockIdx.x * 256 + threadIdx.x;
  atomicAdd(&counts[idx[n]], 1);
}

__global__ __launch_bounds__(256) void kenc(const int* __restrict__ idx,
                                            float2* __restrict__ out2) {
  const int nt = 2048 * 256;
  for (int f2 = blockIdx.x * 256 + threadIdx.x; f2 < 33554432; f2 += nt) {
    const int n  = f2 >> 10;
    const int k  = (f2 & 1023) << 1;
    const int in = idx[n];
    out2[f2] = make_float2(in == k ? 1.f : 0.f, in == (k + 1) ? 1.f : 0.f);
  }
}

__global__ __launch_bounds__(256) void kfinal(const double* __restrict__ loss_accum,
    const int* __restrict__ counts, float* __restrict__ out) {
  __shared__ double sred[256];
  const int t = threadIdx.x;
  double s = 0.0;
  for (int k = t; k < KCODES; k += 256) {
    const double p = counts[k] / 32768.0;
    s += p * log(p + 1e-10);
  }
  sred[t] = s;
  __syncthreads();
  for (int off = 128; off > 0; off >>= 1) {
    if (t < off) sred[t] += sred[t + off];
    __syncthreads();
  }
  if (t == 0) {
    out[0]        = (float)(0.25 * loss_accum[0] / (32768.0 * 512.0));
    out[OUT_PERP] = (float)exp(-sred[0]);
  }
}

extern "C" void kernel_launch(void* const* d_in, const int* in_sizes, int n_in,
                              void* d_out, int out_size, void* d_ws, size_t ws_size,
                              hipStream_t stream) {
  const float* x0  = (const float*)d_in[0];
  const float* x1  = (const float*)d_in[1];
  const float* W   = (const float*)d_in[2];
  const float* b   = (const float*)d_in[3];
  const float* emb = (const float*)d_in[4];
  float* out = (float*)d_out;
  float* S   = out + OUT_ENC + 2;   // 16B-aligned scratch inside encodings region

  double* loss_accum = (double*)d_ws;
  int* counts = (int*)((char*)d_ws + 16);
  int* idx    = (int*)((char*)d_ws + 8208);

  hipMemsetAsync(d_ws, 0, 8208, stream);

  ktranspose<<<dim3(16, 16),  256, 0, stream>>>(W,   S + WT_OFF,   512,   512);
  ktranspose<<<dim3(16, 64),  256, 0, stream>>>(emb, S + EMBT_OFF, 2048,  512);
  ktranspose<<<dim3(8, 1024), 256, 0, stream>>>(x0,  S + XT_OFF,            32768, 256);
  ktranspose<<<dim3(8, 1024), 256, 0, stream>>>(x1,  S + XT_OFF + 8388608,  32768, 256);
  kenorm<<<2048, 64, 0, stream>>>(emb, S + ENORM_OFF);
  kgemm1<<<dim3(512, 4), 256, 0, stream>>>(S + XT_OFF, S + WT_OFF, b,
                                           S + H_OFF, S + HT_OFF);
  kdist<<<512, 256, 0, stream>>>(S + HT_OFF, S + EMBT_OFF, S + ENORM_OFF, idx);
  kquant<<<16384, 256, 0, stream>>>(S + H_OFF, emb, idx, out + OUT_Q, loss_accum);
  khist<<<128, 256, 0, stream>>>(idx, counts);
  kenc<<<2048, 256, 0, stream>>>(idx, (float2*)(out + OUT_ENC));
  kfinal<<<1, 256, 0, stream>>>(loss_accum, counts, out);
}

// Round 3
// 1072.120 us; speedup vs baseline: 1.3778x; 1.3778x over previous
//
#include <hip/hip_runtime.h>
#include <cfloat>
#include <cmath>

#define NROWS 32768
#define DDIM  512
#define KCODES 2048
#define KP    1536   // split-bf16 concatenated K

// output layout (floats): [loss][q_st N*512][perplexity][encodings N*K]
#define OUT_Q    1
#define OUT_PERP 16777217
#define OUT_ENC  16777218

// scratch offsets in float slots, relative to S = d_out + OUT_ENC + 2
// (scratch capacity = 67,108,862 float slots inside the encodings region)
#define H_OFF     0           // 16,777,216
#define WT_OFF    16777216    //    262,144
#define XT_OFF    17039360    // 16,777,216
#define ENORM_OFF 33816576    //      2,048
#define PVAL_OFF  33818624    //  1,048,576 (32 x 32768)
#define PSEC_OFF  34867200    //  1,048,576
#define AP_OFF    35915776    // 25,165,824 (bf16 [32768][1536])
#define BP_OFF    61081600    //  1,572,864 (bf16 [2048][1536])
#define PIDX_OFF  62654464    //  1,048,576 -> end 63,703,040

#define RESCORE_EPS 0.02f

typedef __attribute__((ext_vector_type(8))) short  bf16x8;
typedef __attribute__((ext_vector_type(4))) float  f32x4;

__device__ __forceinline__ unsigned short f2bf(float f) {
  unsigned u = __float_as_uint(f);
  unsigned r = (u + 0x7FFF + ((u >> 16) & 1)) >> 16;
  return (unsigned short)r;
}
__device__ __forceinline__ float bf2f(unsigned short h) {
  return __uint_as_float(((unsigned)h) << 16);
}
__device__ __forceinline__ void gload16(const void* g, void* l) {
  __builtin_amdgcn_global_load_lds(
      (const __attribute__((address_space(1))) unsigned int*)g,
      (__attribute__((address_space(3))) unsigned int*)l, 16, 0, 0);
}

__global__ __launch_bounds__(256) void ktranspose(const float* __restrict__ src,
                                                  float* __restrict__ dst,
                                                  int R, int C) {
  __shared__ float tile[32][33];
  const int bc = blockIdx.x * 32;
  const int br = blockIdx.y * 32;
  const int tx = threadIdx.x & 31;
  const int ty = threadIdx.x >> 5;
#pragma unroll
  for (int i = 0; i < 32; i += 8)
    tile[ty + i][tx] = src[(size_t)(br + ty + i) * C + bc + tx];
  __syncthreads();
#pragma unroll
  for (int i = 0; i < 32; i += 8)
    dst[(size_t)(bc + ty + i) * R + br + tx] = tile[tx][ty + i];
}

__global__ __launch_bounds__(64) void kenorm(const float* __restrict__ emb,
                                             float* __restrict__ enorms) {
  const int k = blockIdx.x;
  const int t = threadIdx.x;
  float s = 0.f;
#pragma unroll
  for (int i = 0; i < 8; ++i) {
    const float v = emb[k * DDIM + t + i * 64];
    s = fmaf(v, v, s);
  }
#pragma unroll
  for (int off = 32; off > 0; off >>= 1) s += __shfl_down(s, off);
  if (t == 0) enorms[k] = s;
}

// B' = [e_hi | e_hi | e_lo] bf16 [2048][1536]
__global__ __launch_bounds__(256) void ksplit_e(const float* __restrict__ emb,
                                                unsigned short* __restrict__ Bp) {
  const int tid = blockIdx.x * 256 + threadIdx.x;   // 1024 blocks
  const int k = tid >> 7;
  const int c = (tid & 127) * 4;
  const float4 e4 = *(const float4*)&emb[(size_t)k * DDIM + c];
  const unsigned short h0 = f2bf(e4.x), h1 = f2bf(e4.y), h2 = f2bf(e4.z), h3 = f2bf(e4.w);
  const unsigned short l0 = f2bf(e4.x - bf2f(h0)), l1 = f2bf(e4.y - bf2f(h1));
  const unsigned short l2 = f2bf(e4.z - bf2f(h2)), l3 = f2bf(e4.w - bf2f(h3));
  const ushort4 hv = make_ushort4(h0, h1, h2, h3);
  const ushort4 lv = make_ushort4(l0, l1, l2, l3);
  unsigned short* row = Bp + (size_t)k * KP;
  *(ushort4*)&row[c]        = hv;
  *(ushort4*)&row[512 + c]  = hv;
  *(ushort4*)&row[1024 + c] = lv;
}

// h = X @ W^T + b; writes h fp32 and A' = [h_hi | h_lo | h_hi] bf16
__global__ __launch_bounds__(256) void kgemm1(const float* __restrict__ xT,
    const float* __restrict__ WT, const float* __restrict__ bias,
    float* __restrict__ h, unsigned short* __restrict__ Ap) {
  __shared__ float Hs[64 * 64];
  __shared__ float Es[64 * 128];
  const int t  = threadIdx.x;
  const int r0 = blockIdx.x * 64;
  const int j0 = blockIdx.y * 128;
  const int tc = t & 15;
  const int tr = t >> 4;
  float acc[4][8];
#pragma unroll
  for (int a = 0; a < 4; ++a)
#pragma unroll
    for (int b2 = 0; b2 < 8; ++b2) acc[a][b2] = 0.f;

  for (int dc = 0; dc < 8; ++dc) {
#pragma unroll
    for (int j = 0; j < 4; ++j) {
      const int dd = j * 16 + (t >> 4);
      const int f  = t & 15;
      *(float4*)&Hs[dd * 64 + f * 4] =
          *(const float4*)&xT[(size_t)(dc * 64 + dd) * NROWS + r0 + f * 4];
    }
#pragma unroll
    for (int j = 0; j < 8; ++j) {
      const int dd = j * 8 + (t >> 5);
      const int c  = t & 31;
      *(float4*)&Es[dd * 128 + c * 4] =
          *(const float4*)&WT[(size_t)(dc * 64 + dd) * DDIM + j0 + c * 4];
    }
    __syncthreads();
#pragma unroll 16
    for (int di = 0; di < 64; ++di) {
      const float4 ha = *(const float4*)&Hs[di * 64 + tr * 4];
      const float4 e0 = *(const float4*)&Es[di * 128 + tc * 4];
      const float4 e1 = *(const float4*)&Es[di * 128 + 64 + tc * 4];
      const float hv[4] = {ha.x, ha.y, ha.z, ha.w};
      const float ev[8] = {e0.x, e0.y, e0.z, e0.w, e1.x, e1.y, e1.z, e1.w};
#pragma unroll
      for (int rr = 0; rr < 4; ++rr)
#pragma unroll
        for (int cc = 0; cc < 8; ++cc)
          acc[rr][cc] = fmaf(hv[rr], ev[cc], acc[rr][cc]);
    }
    __syncthreads();
  }
#pragma unroll
  for (int g = 0; g < 2; ++g) {
    const int j = j0 + g * 64 + tc * 4;
    const float4 bv = *(const float4*)&bias[j];
    const float bb[4] = {bv.x, bv.y, bv.z, bv.w};
#pragma unroll
    for (int rr = 0; rr < 4; ++rr) {
      const int r = r0 + tr * 4 + rr;
      float4 st;
      st.x = acc[rr][g * 4 + 0] + bb[0];
      st.y = acc[rr][g * 4 + 1] + bb[1];
      st.z = acc[rr][g * 4 + 2] + bb[2];
      st.w = acc[rr][g * 4 + 3] + bb[3];
      *(float4*)&h[(size_t)r * DDIM + j] = st;
      const unsigned short h0 = f2bf(st.x), h1 = f2bf(st.y), h2 = f2bf(st.z), h3 = f2bf(st.w);
      const unsigned short l0 = f2bf(st.x - bf2f(h0)), l1 = f2bf(st.y - bf2f(h1));
      const unsigned short l2 = f2bf(st.z - bf2f(h2)), l3 = f2bf(st.w - bf2f(h3));
      unsigned short* arow = Ap + (size_t)r * KP;
      *(ushort4*)&arow[j]        = make_ushort4(h0, h1, h2, h3);
      *(ushort4*)&arow[512 + j]  = make_ushort4(l0, l1, l2, l3);
      *(ushort4*)&arow[1024 + j] = make_ushort4(h0, h1, h2, h3);
    }
  }
}

// MFMA split-bf16 distance GEMM + per-row best/second argmin partials.
// grid 4096 blocks (256 m-panels x 16 n-panels, XCD-swizzled), 256 thr (4 waves 2x2)
// partial slot p = n*2 + wc (each wave-column owns 64 codes -> 32 partials)
__global__ __launch_bounds__(256) void kdist_mfma(
    const unsigned short* __restrict__ Ap, const unsigned short* __restrict__ Bp,
    const float* __restrict__ enorms, float* __restrict__ pval,
    float* __restrict__ psec, int* __restrict__ pidx) {
  __shared__ short Asm[128 * 64];
  __shared__ short Bsm[128 * 64];
  const int bid = blockIdx.x;
  const int m = (bid & 7) * 32 + (bid >> 7);
  const int n = (bid >> 3) & 15;
  const int m0 = m * 128;
  const int n0 = n * 128;
  const int t = threadIdx.x;
  const int wid = t >> 6;
  const int wr = wid >> 1;
  const int wc = wid & 1;
  const int lr = t & 15;
  const int lg = (t >> 4) & 3;

  f32x4 acc[4][4];
#pragma unroll
  for (int mi = 0; mi < 4; ++mi)
#pragma unroll
    for (int ni = 0; ni < 4; ++ni) acc[mi][ni] = (f32x4){0.f, 0.f, 0.f, 0.f};

  for (int kt = 0; kt < KP / 64; ++kt) {
    const unsigned short* Ag = Ap + (size_t)m0 * KP + kt * 64;
    const unsigned short* Bg = Bp + (size_t)n0 * KP + kt * 64;
#pragma unroll
    for (int i = 0; i < 4; ++i) {
      const int chunk = i * 256 + t;
      const int r  = chunk >> 3;
      const int c8 = chunk & 7;
      gload16(Ag + (size_t)r * KP + c8 * 8, &Asm[chunk * 8]);
      gload16(Bg + (size_t)r * KP + c8 * 8, &Bsm[chunk * 8]);
    }
    __syncthreads();
#pragma unroll
    for (int kk = 0; kk < 2; ++kk) {
      bf16x8 a[4], b[4];
#pragma unroll
      for (int mi = 0; mi < 4; ++mi)
        a[mi] = *(const bf16x8*)&Asm[(wr * 64 + mi * 16 + lr) * 64 + kk * 32 + lg * 8];
#pragma unroll
      for (int ni = 0; ni < 4; ++ni)
        b[ni] = *(const bf16x8*)&Bsm[(wc * 64 + ni * 16 + lr) * 64 + kk * 32 + lg * 8];
#pragma unroll
      for (int mi = 0; mi < 4; ++mi)
#pragma unroll
        for (int ni = 0; ni < 4; ++ni)
          acc[mi][ni] = __builtin_amdgcn_mfma_f32_16x16x32_bf16(a[mi], b[ni], acc[mi][ni], 0, 0, 0);
    }
    __syncthreads();
  }

  // epilogue: d2 = ||e||^2 - 2 dot ; per-row best/second across this wave's 64 codes
  float en[4]; int kb[4];
#pragma unroll
  for (int ni = 0; ni < 4; ++ni) {
    kb[ni] = n0 + wc * 64 + ni * 16 + lr;
    en[ni] = enorms[kb[ni]];
  }
  const int p = n * 2 + wc;
#pragma unroll
  for (int mi = 0; mi < 4; ++mi)
#pragma unroll
    for (int j = 0; j < 4; ++j) {
      float bv = fmaf(-2.f, acc[mi][0][j], en[0]);
      int bk = kb[0];
      float sv = FLT_MAX;
#pragma unroll
      for (int ni = 1; ni < 4; ++ni) {
        const float v = fmaf(-2.f, acc[mi][ni][j], en[ni]);
        if (v < bv) { sv = bv; bv = v; bk = kb[ni]; }
        else sv = fminf(sv, v);
      }
#pragma unroll
      for (int msk = 1; msk < 16; msk <<= 1) {
        const float ob = __shfl_xor(bv, msk);
        const int   ok = __shfl_xor(bk, msk);
        const float os = __shfl_xor(sv, msk);
        if (ob < bv || (ob == bv && ok < bk)) { sv = fminf(bv, os); bv = ob; bk = ok; }
        else sv = fminf(sv, ob);
      }
      if (lr == 0) {
        const int row = m0 + wr * 64 + mi * 16 + lg * 4 + j;
        pval[p * NROWS + row] = bv;
        psec[p * NROWS + row] = sv;
        pidx[p * NROWS + row] = bk;
      }
    }
}

// merge 32 panel partials -> global best; flag ambiguous rows
__global__ __launch_bounds__(256) void kreduce(const float* __restrict__ pval,
    const float* __restrict__ psec, const int* __restrict__ pidx,
    int* __restrict__ idx, int* __restrict__ nflag, int* __restrict__ flags) {
  const int r = blockIdx.x * 256 + threadIdx.x;
  float bv = FLT_MAX, sv = FLT_MAX;
  int bk = 0;
#pragma unroll
  for (int p = 0; p < 32; ++p) {
    const float v1 = pval[p * NROWS + r];
    const int   k1 = pidx[p * NROWS + r];
    const float s1 = psec[p * NROWS + r];
    if (v1 < bv || (v1 == bv && k1 < bk)) { sv = fminf(bv, s1); bv = v1; bk = k1; }
    else sv = fminf(sv, v1);
  }
  idx[r] = bk;
  if (sv - bv < RESCORE_EPS) {
    const int pos = atomicAdd(nflag, 1);
    flags[pos] = r;
  }
}

// exact fp32 rescore over all 2048 codes for flagged rows
__global__ __launch_bounds__(256) void krescore(const float* __restrict__ h,
    const float* __restrict__ emb, const float* __restrict__ enorms,
    const int* __restrict__ flags, const int* __restrict__ nflag,
    int* __restrict__ idx) {
  __shared__ float hr[512];
  __shared__ float rv[256];
  __shared__ int   rk[256];
  const int t = threadIdx.x;
  const int nf = *nflag;
  for (int f = blockIdx.x; f < nf; f += gridDim.x) {
    const int r = flags[f];
    __syncthreads();
    if (t < 128) ((float4*)hr)[t] = ((const float4*)(h + (size_t)r * DDIM))[t];
    __syncthreads();
    float bv = FLT_MAX; int bk = 0;
    for (int k = t; k < KCODES; k += 256) {
      float dot = 0.f;
#pragma unroll 8
      for (int d = 0; d < DDIM; d += 4) {
        const float4 e4 = *(const float4*)&emb[(size_t)k * DDIM + d];
        dot = fmaf(hr[d], e4.x, dot);
        dot = fmaf(hr[d + 1], e4.y, dot);
        dot = fmaf(hr[d + 2], e4.z, dot);
        dot = fmaf(hr[d + 3], e4.w, dot);
      }
      const float v = fmaf(-2.f, dot, enorms[k]);
      if (v < bv) { bv = v; bk = k; }
    }
    rv[t] = bv; rk[t] = bk;
    __syncthreads();
    for (int off = 128; off > 0; off >>= 1) {
      if (t < off) {
        const float v2 = rv[t + off];
        const int   k2 = rk[t + off];
        if (v2 < rv[t] || (v2 == rv[t] && k2 < rk[t])) { rv[t] = v2; rk[t] = k2; }
      }
      __syncthreads();
    }
    if (t == 0) idx[r] = rk[0];
  }
}

__global__ __launch_bounds__(256) void kquant(const float* __restrict__ h,
    const float* __restrict__ emb, const int* __restrict__ idx,
    float* __restrict__ qout, double* __restrict__ loss_accum) {
  const int tid = blockIdx.x * 256 + threadIdx.x;
  float ls = 0.f;
#pragma unroll
  for (int i = 0; i < 4; ++i) {
    const int f = tid + i * 4194304;
    const int n = f >> 9;
    const int c = f & 511;
    const float hv = h[f];
    const float ev = emb[(size_t)idx[n] * DDIM + c];
    qout[f] = hv + (ev - hv);
    const float d = ev - hv;
    ls = fmaf(d, d, ls);
  }
  double s = (double)ls;
#pragma unroll
  for (int off = 32; off > 0; off >>= 1) s += __shfl_down(s, off);
  __shared__ double sred[4];
  if ((threadIdx.x & 63) == 0) sred[threadIdx.x >> 6] = s;
  __syncthreads();
  if (threadIdx.x == 0)
    atomicAdd(loss_accum, sred[0] + sred[1] + sred[2] + sred[3]);
}

__global__ __launch_bounds__(256) void khist(const int* __restrict__ idx,
                                             int* __restrict__ counts) {
  const int n = blockIdx.x * 256 + threadIdx.x;
  atomicAdd(&counts[idx[n]], 1);
}

__global__ __launch_bounds__(256) void kenc(const int* __restrict__ idx,
                                            float2* __restrict__ out2) {
  const int nt = 2048 * 256;
  for (int f2 = blockIdx.x * 256 + threadIdx.x; f2 < 33554432; f2 += nt) {
    const int n  = f2 >> 10;
    const int k  = (f2 & 1023) << 1;
    const int in = idx[n];
    out2[f2] = make_float2(in == k ? 1.f : 0.f, in == (k + 1) ? 1.f : 0.f);
  }
}

__global__ __launch_bounds__(256) void kfinal(const double* __restrict__ loss_accum,
    const int* __restrict__ counts, float* __restrict__ out) {
  __shared__ double sred[256];
  const int t = threadIdx.x;
  double s = 0.0;
  for (int k = t; k < KCODES; k += 256) {
    const double p = counts[k] / 32768.0;
    s += p * log(p + 1e-10);
  }
  sred[t] = s;
  __syncthreads();
  for (int off = 128; off > 0; off >>= 1) {
    if (t < off) sred[t] += sred[t + off];
    __syncthreads();
  }
  if (t == 0) {
    out[0]        = (float)(0.25 * loss_accum[0] / (32768.0 * 512.0));
    out[OUT_PERP] = (float)exp(-sred[0]);
  }
}

extern "C" void kernel_launch(void* const* d_in, const int* in_sizes, int n_in,
                              void* d_out, int out_size, void* d_ws, size_t ws_size,
                              hipStream_t stream) {
  const float* x0  = (const float*)d_in[0];
  const float* x1  = (const float*)d_in[1];
  const float* W   = (const float*)d_in[2];
  const float* b   = (const float*)d_in[3];
  const float* emb = (const float*)d_in[4];
  float* out = (float*)d_out;
  float* S   = out + OUT_ENC + 2;

  unsigned short* Ap = (unsigned short*)(S + AP_OFF);
  unsigned short* Bp = (unsigned short*)(S + BP_OFF);
  int* pidx = (int*)(S + PIDX_OFF);

  double* loss_accum = (double*)d_ws;
  int* nflag  = (int*)((char*)d_ws + 8);
  int* counts = (int*)((char*)d_ws + 16);
  int* idx    = (int*)((char*)d_ws + 8208);
  int* flags  = (int*)((char*)d_ws + 139280);

  hipMemsetAsync(d_ws, 0, 8208, stream);

  ktranspose<<<dim3(16, 16),  256, 0, stream>>>(W,  S + WT_OFF, 512, 512);
  ktranspose<<<dim3(8, 1024), 256, 0, stream>>>(x0, S + XT_OFF,           32768, 256);
  ktranspose<<<dim3(8, 1024), 256, 0, stream>>>(x1, S + XT_OFF + 8388608, 32768, 256);
  kenorm<<<2048, 64, 0, stream>>>(emb, S + ENORM_OFF);
  ksplit_e<<<1024, 256, 0, stream>>>(emb, Bp);
  kgemm1<<<dim3(512, 4), 256, 0, stream>>>(S + XT_OFF, S + WT_OFF, b, S + H_OFF, Ap);
  kdist_mfma<<<4096, 256, 0, stream>>>(Ap, Bp, S + ENORM_OFF,
                                       S + PVAL_OFF, S + PSEC_OFF, pidx);
  kreduce<<<128, 256, 0, stream>>>(S + PVAL_OFF, S + PSEC_OFF, pidx, idx, nflag, flags);
  krescore<<<120, 256, 0, stream>>>(S + H_OFF, emb, S + ENORM_OFF, flags, nflag, idx);
  kquant<<<16384, 256, 0, stream>>>(S + H_OFF, emb, idx, out + OUT_Q, loss_accum);
  khist<<<128, 256, 0, stream>>>(idx, counts);
  kenc<<<2048, 256, 0, stream>>>(idx, (float2*)(out + OUT_ENC));
  kfinal<<<1, 256, 0, stream>>>(loss_accum, counts, out);
}